// Round 4
// baseline (79.666 us; speedup 1.0000x reference)
//
#include <hip/hip_runtime.h>

// RadiusInteractionGraph — f32 in, f32 out; reference compared in bf16.
// Base: R7 harness-verified kernel (absmax==0.0, 72.9 us). Conventions:
// pad row=0, col=i always, pad w=0, pad mask=0; self-loop row=col=i, w=0,
// mask=1; all emitted values bf16-rounded (RNE) then expanded to f32.
// d2 pipeline mirrors np gram-trick op order exactly.
//
// R10 (minimal-delta retest of LDS staging; R8/R9 post-mortem):
//  * R8 and R9 both failed with the bit-identical absmax (576.0) despite
//    disjoint mechanisms; R9's run shows artifact-caching signatures
//    (anomalously fast push/pytest). Since pos is bf16-quantized, all
//    products in the d2 chain are exact in f32 -> codegen shape cannot
//    change d2 bits; no semantic path from R9 source to a wrong output
//    was found. R10 retests the staging design at the minimal possible
//    delta, with renamed kernels (k10_*) to bust any build cache.
//  * ONLY change vs R7: the scan's j-side (xj,yj,zj) come from an LDS
//    bitwise copy of pos (staged with pure moves, NO FP math). x2j is
//    still recomputed PER-LANE with the exact R7 expression. Center
//    reads, weight reads, compaction order, rank tie-break, and all
//    output writes are byte-identical to R7's verified paths.
//  * Stage covers the block's contiguous index range [S, Eu) (union of
//    its 4 centers' segments, incl. any batches in between). o >= CAP
//    falls back to R7's direct global loads (bit-identical).

#define NPTS 8192
#define KNN 32
#define NG 8
#define MAXC 192
#define CAP 1792
#define EDGES (NPTS * KNN + NPTS)   // 270336

__device__ int g_bounds_k10[NG + 1];  // bounds[g] = first idx with batch >= g

__device__ __forceinline__ float bfq(float f) {
    // quantize f32 -> bf16 grid (RNE), return as f32
    union { float f; unsigned int i; } v;
    v.f = f;
    unsigned int b = v.i;
    unsigned int r = (b + 0x7FFFu + ((b >> 16) & 1u)) & 0xFFFF0000u;
    v.i = r;
    return v.f;
}

// batch storage detection: int32 -> word[N-1] = last batch id = NG-1;
// int64 -> word[N-1] is the HIGH word of element N/2-1 = 0.
__device__ __forceinline__ int batch_stride(const int* __restrict__ b) {
    return (b[NPTS - 1] != NG - 1) ? 2 : 1;
}

__global__ __launch_bounds__(256) void k10_bounds(
        const int* __restrict__ batch32) {
    const int tid = blockIdx.x * 256 + threadIdx.x;
    if (tid >= NPTS) return;
    const int stride = batch_stride(batch32);
    const int g  = batch32[tid * stride];
    const int gp = (tid == 0) ? -1 : batch32[(tid - 1) * stride];
    for (int v = gp + 1; v <= g; ++v) g_bounds_k10[v] = tid;
    if (tid == NPTS - 1) {
        for (int v = g + 1; v <= NG; ++v) g_bounds_k10[v] = NPTS;
    }
}

__global__ __launch_bounds__(256) void k10_radius(
        const float* __restrict__ pos,       // f32 [N,3]
        const int*   __restrict__ batch32,   // int32 (or int64 low/high words)
        float*       __restrict__ out) {     // f32 [4E]
    const int wave = threadIdx.x >> 6;
    const int lane = threadIdx.x & 63;
    const int i = (blockIdx.x << 2) + wave;  // center node (one wave each)

    __shared__ float4 s_pos[CAP];            // bitwise copy of pos (w unused)
    __shared__ float2 s_cand[4][MAXC];       // {d2, idx-as-float-bits}

    const int stride = batch_stride(batch32);
    const int g = batch32[i * stride];
    const int s = g_bounds_k10[g];
    const int e = g_bounds_k10[g + 1];

    // block-level contiguous stage range [S, Eu) spanning all 4 centers
    const int i0 = blockIdx.x << 2;
    const int g0 = batch32[i0 * stride];
    const int g3 = batch32[(i0 + 3) * stride];
    const int S  = g_bounds_k10[g0];
    const int Eu = g_bounds_k10[g3 + 1];

    // cooperative stage: PURE MOVES (no FP math) — bitwise pos copy
    for (int o = (int)threadIdx.x; o < CAP; o += 256) {
        const int n = S + o;
        if (n >= Eu) break;
        s_pos[o] = make_float4(pos[3 * n + 0], pos[3 * n + 1],
                               pos[3 * n + 2], 0.0f);
    }
    __syncthreads();

    // center data: DIRECT global reads, exactly as verified R7
    const float xi = pos[3 * i + 0];
    const float yi = pos[3 * i + 1];
    const float zi = pos[3 * i + 2];
    const float x2i = __fadd_rn(__fadd_rn(__fmul_rn(xi, xi), __fmul_rn(yi, yi)),
                                __fmul_rn(zi, zi));

    // scan own batch segment; ballot-prefix compaction into wave-private LDS
    int cnt = 0;
    for (int j0 = s; j0 < e; j0 += 64) {
        const int j = j0 + lane;
        bool ok = false;
        float d2 = 0.0f;
        if (j < e && j != i) {
            const int o = j - S;
            float xj, yj, zj;
            if (o < CAP) {
                const float4 pj = s_pos[o];
                xj = pj.x; yj = pj.y; zj = pj.z;
            } else {           // overflow fallback: R7's direct loads
                xj = pos[3 * j + 0];
                yj = pos[3 * j + 1];
                zj = pos[3 * j + 2];
            }
            // x2j per-lane, exact R7 expression (np order, each op rounded)
            const float x2j = __fadd_rn(
                __fadd_rn(__fmul_rn(xj, xj), __fmul_rn(yj, yj)),
                __fmul_rn(zj, zj));
            // dot: ascending-k FMA chain (== mul+add chain, products exact)
            float dot = __fmul_rn(xi, xj);
            dot = __fmaf_rn(yi, yj, dot);
            dot = __fmaf_rn(zi, zj, dot);
            // d2 = (x2i + x2j) - 2*dot, np gram-trick expression order
            d2 = __fsub_rn(__fadd_rn(x2i, x2j), __fmul_rn(2.0f, dot));
            ok = (d2 <= 100.0f);
        }
        const unsigned long long m = __ballot(ok);
        if (ok) {
            const int p = cnt + __popcll(m & ((1ull << lane) - 1ull));
            if (p < MAXC) s_cand[wave][p] = make_float2(d2, __int_as_float(j));
        }
        cnt += (int)__popcll(m);
    }
    cnt = min(cnt, MAXC);
    __syncthreads();   // orders LDS writes before reads

    const int E = EDGES;
    const float fci = bfq((float)i);     // bf16-grid center index
    const int ne = min(cnt, KNN);

    // exact rank of candidate c: ascending d2, ties -> lower index first
    // (matches jax.lax.top_k stable tie behavior)
    for (int c = lane; c < cnt; c += 64) {
        const float2 pc = s_cand[wave][c];
        const float dc = pc.x;
        const int   ic = __float_as_int(pc.y);
        int rank = 0;
        for (int q = 0; q < cnt; ++q) {
            const float2 pq = s_cand[wave][q];    // broadcast ds_read_b64
            const float dq = pq.x;
            if (dq < dc || (dq == dc && __float_as_int(pq.y) < ic)) rank++;
        }
        if (rank < KNN) {
            const int slot = i * KNN + rank;
            // weight = ||pos[row]-pos[col]||: DIRECT global reads (R7 path)
            const float dx = __fsub_rn(pos[3 * ic + 0], xi);
            const float dy = __fsub_rn(pos[3 * ic + 1], yi);
            const float dz = __fsub_rn(pos[3 * ic + 2], zi);
            const float sq = __fadd_rn(
                __fadd_rn(__fmul_rn(dx, dx), __fmul_rn(dy, dy)),
                __fmul_rn(dz, dz));
            const float w = (sq > 0.0f) ? __fsqrt_rn(sq) : 0.0f;
            out[slot]         = bfq((float)ic);  // row = neighbor (source)
            out[E + slot]     = fci;             // col = center (target)
            out[2 * E + slot] = bfq(w);          // weight
            out[3 * E + slot] = 1.0f;            // mask
        }
    }
    // padded slots: row=0 (where(mask,row,0)), col=i, weight=0, mask=0
    for (int c = ne + lane; c < KNN; c += 64) {
        const int slot = i * KNN + c;
        out[slot]         = 0.0f;
        out[E + slot]     = fci;
        out[2 * E + slot] = 0.0f;
        out[3 * E + slot] = 0.0f;
    }
    // self-loop appended at end: row=col=i, weight 0, mask 1
    if (lane == 0) {
        const int slot = NPTS * KNN + i;
        out[slot]         = fci;
        out[E + slot]     = fci;
        out[2 * E + slot] = 0.0f;
        out[3 * E + slot] = 1.0f;
    }
}

extern "C" void kernel_launch(void* const* d_in, const int* in_sizes, int n_in,
                              void* d_out, int out_size, void* d_ws, size_t ws_size,
                              hipStream_t stream) {
    const float* pos   = (const float*)d_in[0];   // f32 [N,3]
    const int* batch32 = (const int*)d_in[1];     // int32 (int64 tolerated)
    float* out = (float*)d_out;                   // f32 [4E]

    k10_bounds<<<32, 256, 0, stream>>>(batch32);
    k10_radius<<<2048, 256, 0, stream>>>(pos, batch32, out);
}

// Round 7
// 71.338 us; speedup vs baseline: 1.1168x; 1.1168x over previous
//
#include <hip/hip_runtime.h>

// RadiusInteractionGraph — f32 in, f32 out; reference compared in bf16.
// Base: R7 harness-verified kernel (absmax==0.0, 72.9 us). Conventions:
// pad row=0, col=i always, pad w=0, pad mask=0; self-loop row=col=i, w=0,
// mask=1; all emitted values bf16-rounded (RNE) then expanded to f32.
// d2 pipeline mirrors np gram-trick op order exactly (pos is
// bf16-quantized -> every product is exact in f32).
//
// R13 == R12 resubmitted verbatim (R12 hit an infra failure: "MI355X
// container failed twice" — no kernel verdict was produced). Symbols
// renamed k13_* to bust any stale build/artifact cache on the retry.
//
// R12 rationale (R11 post-mortem applied):
//  * R11 (cross-wave atomic insertion + register blocking) failed with a
//    real absmax 448 whose mechanism resisted inspection. Reverted to the
//    R7-verified per-wave structure wholesale — no cross-wave insertion,
//    no register blocking, no LDS pos copy (R10: staging is a net loss),
//    no cross-kernel bulk state (R8 lesson).
//  * ONLY change vs R7: the scan is unrolled x2 with both iterations'
//    global loads hoisted above the dependent math/ballot — pure
//    reordering of independent per-wave work. Insertion order (ascending
//    j), candidate set, d2 bits, rank tie-break, and every output write
//    are byte-identical to R7.

#define NPTS 8192
#define KNN 32
#define NG 8
#define MAXC 192
#define EDGES (NPTS * KNN + NPTS)   // 270336

__device__ int g_bounds_k13[NG + 1];  // bounds[g] = first idx with batch >= g

__device__ __forceinline__ float bfq(float f) {
    // quantize f32 -> bf16 grid (RNE), return as f32
    union { float f; unsigned int i; } v;
    v.f = f;
    unsigned int b = v.i;
    unsigned int r = (b + 0x7FFFu + ((b >> 16) & 1u)) & 0xFFFF0000u;
    v.i = r;
    return v.f;
}

// batch storage detection: int32 -> word[N-1] = last batch id = NG-1;
// int64 -> word[N-1] is the HIGH word of element N/2-1 = 0.
__device__ __forceinline__ int batch_stride(const int* __restrict__ b) {
    return (b[NPTS - 1] != NG - 1) ? 2 : 1;
}

__global__ __launch_bounds__(256) void k13_bounds(
        const int* __restrict__ batch32) {
    const int tid = blockIdx.x * 256 + threadIdx.x;
    if (tid >= NPTS) return;
    const int stride = batch_stride(batch32);
    const int g  = batch32[tid * stride];
    const int gp = (tid == 0) ? -1 : batch32[(tid - 1) * stride];
    for (int v = gp + 1; v <= g; ++v) g_bounds_k13[v] = tid;
    if (tid == NPTS - 1) {
        for (int v = g + 1; v <= NG; ++v) g_bounds_k13[v] = NPTS;
    }
}

__global__ __launch_bounds__(256) void k13_radius(
        const float* __restrict__ pos,       // f32 [N,3]
        const int*   __restrict__ batch32,   // int32 (or int64 low/high words)
        float*       __restrict__ out) {     // f32 [4E]
    const int wave = threadIdx.x >> 6;
    const int lane = threadIdx.x & 63;
    const int i = (blockIdx.x << 2) + wave;  // center node (one wave each)

    __shared__ float2 s_cand[4][MAXC];       // {d2, idx-as-float-bits}

    const int stride = batch_stride(batch32);
    const int g = batch32[i * stride];
    const int s = g_bounds_k13[g];
    const int e = g_bounds_k13[g + 1];

    // |p_i|^2 in np order: (x*x + y*y) + z*z, each op separately rounded.
    const float xi = pos[3 * i + 0];
    const float yi = pos[3 * i + 1];
    const float zi = pos[3 * i + 2];
    const float x2i = __fadd_rn(__fadd_rn(__fmul_rn(xi, xi), __fmul_rn(yi, yi)),
                                __fmul_rn(zi, zi));

    // scan own batch segment; per-wave ballot-prefix compaction (R7 path),
    // unrolled x2 with all 6 loads hoisted above the dependent math.
    int cnt = 0;
    int j0 = s;
    for (; j0 + 128 <= e; j0 += 128) {
        const int ja = j0 + lane;
        const int jb = ja + 64;
        const float xa = pos[3 * ja + 0];
        const float ya = pos[3 * ja + 1];
        const float za = pos[3 * ja + 2];
        const float xb = pos[3 * jb + 0];
        const float yb = pos[3 * jb + 1];
        const float zb = pos[3 * jb + 2];
        {   // --- block a (identical formula to R7) ---
            const float x2j = __fadd_rn(
                __fadd_rn(__fmul_rn(xa, xa), __fmul_rn(ya, ya)),
                __fmul_rn(za, za));
            float dot = __fmul_rn(xi, xa);
            dot = __fmaf_rn(yi, ya, dot);
            dot = __fmaf_rn(zi, za, dot);
            const float d2 = __fsub_rn(__fadd_rn(x2i, x2j),
                                       __fmul_rn(2.0f, dot));
            const bool ok = (ja != i) && (d2 <= 100.0f);
            const unsigned long long m = __ballot(ok);
            if (ok) {
                const int p = cnt + (int)__popcll(m & ((1ull << lane) - 1ull));
                if (p < MAXC) s_cand[wave][p] = make_float2(d2, __int_as_float(ja));
            }
            cnt += (int)__popcll(m);
        }
        {   // --- block b ---
            const float x2j = __fadd_rn(
                __fadd_rn(__fmul_rn(xb, xb), __fmul_rn(yb, yb)),
                __fmul_rn(zb, zb));
            float dot = __fmul_rn(xi, xb);
            dot = __fmaf_rn(yi, yb, dot);
            dot = __fmaf_rn(zi, zb, dot);
            const float d2 = __fsub_rn(__fadd_rn(x2i, x2j),
                                       __fmul_rn(2.0f, dot));
            const bool ok = (jb != i) && (d2 <= 100.0f);
            const unsigned long long m = __ballot(ok);
            if (ok) {
                const int p = cnt + (int)__popcll(m & ((1ull << lane) - 1ull));
                if (p < MAXC) s_cand[wave][p] = make_float2(d2, __int_as_float(jb));
            }
            cnt += (int)__popcll(m);
        }
    }
    for (; j0 < e; j0 += 64) {     // remainder: R7 verbatim
        const int j = j0 + lane;
        bool ok = false;
        float d2 = 0.0f;
        if (j < e && j != i) {
            const float xj = pos[3 * j + 0];
            const float yj = pos[3 * j + 1];
            const float zj = pos[3 * j + 2];
            const float x2j = __fadd_rn(
                __fadd_rn(__fmul_rn(xj, xj), __fmul_rn(yj, yj)),
                __fmul_rn(zj, zj));
            float dot = __fmul_rn(xi, xj);
            dot = __fmaf_rn(yi, yj, dot);
            dot = __fmaf_rn(zi, zj, dot);
            d2 = __fsub_rn(__fadd_rn(x2i, x2j), __fmul_rn(2.0f, dot));
            ok = (d2 <= 100.0f);
        }
        const unsigned long long m = __ballot(ok);
        if (ok) {
            const int p = cnt + (int)__popcll(m & ((1ull << lane) - 1ull));
            if (p < MAXC) s_cand[wave][p] = make_float2(d2, __int_as_float(j));
        }
        cnt += (int)__popcll(m);
    }
    cnt = min(cnt, MAXC);
    __syncthreads();   // orders LDS writes before reads

    const int E = EDGES;
    const float fci = bfq((float)i);     // bf16-grid center index
    const int ne = min(cnt, KNN);

    // exact rank of candidate c: ascending d2, ties -> lower index first
    // (matches jax.lax.top_k stable tie behavior)
    for (int c = lane; c < cnt; c += 64) {
        const float2 pc = s_cand[wave][c];
        const float dc = pc.x;
        const int   ic = __float_as_int(pc.y);
        int rank = 0;
        for (int q = 0; q < cnt; ++q) {
            const float2 pq = s_cand[wave][q];    // broadcast ds_read_b64
            const float dq = pq.x;
            if (dq < dc || (dq == dc && __float_as_int(pq.y) < ic)) rank++;
        }
        if (rank < KNN) {
            const int slot = i * KNN + rank;
            // weight = ||pos[row]-pos[col]||, np order (R7 verbatim)
            const float dx = __fsub_rn(pos[3 * ic + 0], xi);
            const float dy = __fsub_rn(pos[3 * ic + 1], yi);
            const float dz = __fsub_rn(pos[3 * ic + 2], zi);
            const float sq = __fadd_rn(
                __fadd_rn(__fmul_rn(dx, dx), __fmul_rn(dy, dy)),
                __fmul_rn(dz, dz));
            const float w = (sq > 0.0f) ? __fsqrt_rn(sq) : 0.0f;
            out[slot]         = bfq((float)ic);  // row = neighbor (source)
            out[E + slot]     = fci;             // col = center (target)
            out[2 * E + slot] = bfq(w);          // weight
            out[3 * E + slot] = 1.0f;            // mask
        }
    }
    // padded slots: row=0 (where(mask,row,0)), col=i, weight=0, mask=0
    for (int c = ne + lane; c < KNN; c += 64) {
        const int slot = i * KNN + c;
        out[slot]         = 0.0f;
        out[E + slot]     = fci;
        out[2 * E + slot] = 0.0f;
        out[3 * E + slot] = 0.0f;
    }
    // self-loop appended at end: row=col=i, weight 0, mask 1
    if (lane == 0) {
        const int slot = NPTS * KNN + i;
        out[slot]         = fci;
        out[E + slot]     = fci;
        out[2 * E + slot] = 0.0f;
        out[3 * E + slot] = 1.0f;
    }
}

extern "C" void kernel_launch(void* const* d_in, const int* in_sizes, int n_in,
                              void* d_out, int out_size, void* d_ws, size_t ws_size,
                              hipStream_t stream) {
    const float* pos   = (const float*)d_in[0];   // f32 [N,3]
    const int* batch32 = (const int*)d_in[1];     // int32 (int64 tolerated)
    float* out = (float*)d_out;                   // f32 [4E]

    k13_bounds<<<32, 256, 0, stream>>>(batch32);
    k13_radius<<<2048, 256, 0, stream>>>(pos, batch32, out);
}